// Round 4
// baseline (50.331 us; speedup 1.0000x reference)
//
#include <hip/hip_runtime.h>
#include <hip/hip_bf16.h>

#define TWOPI_OVER_B 0.049087385212340517f  // 2*pi/128

typedef __attribute__((ext_vector_type(8))) short bf16x8;
typedef __attribute__((ext_vector_type(4))) float f32x4;

static __device__ __forceinline__ unsigned short f2bf(float f) {
    __hip_bfloat16 h = __float2bfloat16(f);
    return *reinterpret_cast<unsigned short*>(&h);
}
static __device__ __forceinline__ unsigned long long pack4(float a, float b, float c, float d) {
    return (unsigned long long)f2bf(a) | ((unsigned long long)f2bf(b) << 16)
         | ((unsigned long long)f2bf(c) << 32) | ((unsigned long long)f2bf(d) << 48);
}

// ---------------------------------------------------------------------------
// Prep: blocks 0..79 build fragB (stage-A B-operand, DFT matrix, fragment
// order) + fragCi (stage-C iDFT matrix). Blocks 80..95 build BmatT[k][o2][j2]
// (real-expanded, conj/scale-folded W spectrum) via MFMA DFT, computing their
// own B-frags into LDS with sincos (no cross-block dependency).
__global__ __launch_bounds__(256) void k_prep(const float* __restrict__ W,
                                              unsigned short* __restrict__ fragB,
                                              unsigned short* __restrict__ fragCi,
                                              unsigned short* __restrict__ BmatT) {
    __shared__ char smem[73984];
    int tid = threadIdx.x;

    if (blockIdx.x < 80) {
        int i = blockIdx.x * 256 + tid;
        if (i < 18432) {                       // fragB: ((c*4+kb)*64 + l)*8 + e
            int e = i & 7, l2 = (i >> 3) & 63, kb = (i >> 9) & 3, c = i >> 11;
            int kr = c * 16 + (l2 & 15);
            int t  = kb * 32 + (l2 >> 4) * 8 + e;
            float v = 0.f;
            if (kr < 65)       v =  cosf(TWOPI_OVER_B * (float)((kr * t) & 127));
            else if (kr < 130) v = -sinf(TWOPI_OVER_B * (float)(((kr - 65) * t) & 127));
            fragB[i] = f2bf(v);
        }
        if (i < 20480) {                       // fragCi: ((c*5+kb)*64 + l)*8 + e
            int e = i & 7, l2 = (i >> 3) & 63;
            int ckb = i >> 9; int kb = ckb % 5, c = ckb / 5;
            int kr = kb * 32 + (l2 >> 4) * 8 + e;
            int t  = c * 16 + (l2 & 15);
            float v = 0.f;
            if (kr < 65)       v =  cosf(TWOPI_OVER_B * (float)((kr * t) & 127));
            else if (kr < 130) v = -sinf(TWOPI_OVER_B * (float)(((kr - 65) * t) & 127));
            fragCi[i] = f2bf(v);
        }
        return;
    }

    int bw = blockIdx.x - 80;                  // 0..15, 2 o's each
    unsigned long long* xs8 = (unsigned long long*)smem;
    float* Yl = (float*)smem;                  // [0,37120)
    unsigned short* fB = (unsigned short*)(smem + 37120);  // 36864B

    for (int i = tid; i < 18432; i += 256) {   // local fragB via sincos
        int e = i & 7, l2 = (i >> 3) & 63, kb = (i >> 9) & 3, c = i >> 11;
        int kr = c * 16 + (l2 & 15);
        int t  = kb * 32 + (l2 >> 4) * 8 + e;
        float v = 0.f;
        if (kr < 65)       v =  cosf(TWOPI_OVER_B * (float)((kr * t) & 127));
        else if (kr < 130) v = -sinf(TWOPI_OVER_B * (float)(((kr - 65) * t) & 127));
        fB[i] = f2bf(v);
    }
    #pragma unroll
    for (int it = 0; it < 8; ++it) {           // 64 rows x 128 = 2048 float4
        int f  = tid + it * 256;
        float4 wa = ((const float4*)W)[(size_t)bw * 2048 + f];
        int rl = f >> 5;
        int t0 = (f & 31) * 4;
        int byte = (rl * 256 + t0 * 2) ^ ((rl & 7) << 4);
        xs8[byte >> 3] = pack4(wa.x, wa.y, wa.z, wa.w);
    }
    __syncthreads();

    int l = tid & 63, w = tid >> 6;
    int rl_a = w * 16 + (l & 15);
    int coff = (l >> 4) * 16;
    bf16x8 a[4];
    #pragma unroll
    for (int kb = 0; kb < 4; ++kb) {
        int byte = (rl_a * 256 + kb * 64 + coff) ^ ((rl_a & 7) << 4);
        a[kb] = *(const bf16x8*)(smem + byte);
    }
    __syncthreads();                           // xs dead; Yl overwrites

    f32x4 acc[9];
    #pragma unroll
    for (int c = 0; c < 9; ++c) acc[c] = (f32x4)0.f;
    #pragma unroll
    for (int c = 0; c < 9; ++c)
        #pragma unroll
        for (int kb = 0; kb < 4; ++kb)
            acc[c] = __builtin_amdgcn_mfma_f32_16x16x32_bf16(a[kb], ((const bf16x8*)fB)[(c * 4 + kb) * 64 + l], acc[c], 0, 0, 0);

    int rowd = w * 16 + (l >> 4) * 4;
    int cold = l & 15;
    #pragma unroll
    for (int c = 0; c < 9; ++c)
        #pragma unroll
        for (int r = 0; r < 4; ++r)
            Yl[(rowd + r) * 145 + c * 16 + cold] = acc[c][r];
    __syncthreads();

    int o0 = bw * 2;
    for (int c2 = tid; c2 < 4160; c2 += 256) {
        int k = c2 >> 6, sub = c2 & 63;
        int oo = sub >> 5, h = (sub >> 4) & 1, t = sub & 15;
        int j0 = t * 4;
        float sc = (k == 0 || k == 64) ? (1.f / 128.f) : (2.f / 128.f);
        int col; float sgn;
        if (j0 < 32) { col = h ? 65 + k : k;  sgn = h ? -sc : sc; }
        else         { col = h ? k : 65 + k;  sgn = sc; }
        int rlb = oo * 32 + (j0 & 31);
        unsigned long long pk = pack4(sgn * Yl[(rlb + 0) * 145 + col], sgn * Yl[(rlb + 1) * 145 + col],
                                      sgn * Yl[(rlb + 2) * 145 + col], sgn * Yl[(rlb + 3) * 145 + col]);
        int o2 = h * 32 + o0 + oo;
        *(unsigned long long*)(BmatT + ((size_t)k * 64 + o2) * 64 + j0) = pk;
    }
}

// ---------------------------------------------------------------------------
// Fused A+B+C: per block, 4 batch rows end-to-end in LDS.
//  xs  [0,32768)      : x*D bf16, 128 rows(4n x 32j) x 128t, XOR-swizzled
//  Xl  [0,33280)      : X[k][nn][j2] bf16 (overlaps xs; barrier-separated)
//  ys  [33280,74240)  : [128 (nn,o) rows][160 kr] bf16, XOR-swizzled
#define YS_OFF 33280
__global__ __launch_bounds__(512, 4) void k_fused(const float* __restrict__ x,
                                                  const float* __restrict__ D,
                                                  const bf16x8* __restrict__ fragB,
                                                  const bf16x8* __restrict__ fragCi,
                                                  const unsigned short* __restrict__ BmatT,
                                                  float* __restrict__ out) {
    __shared__ char smem[74240];
    unsigned long long* xs8 = (unsigned long long*)smem;
    int tid = threadIdx.x, l = tid & 63, w = tid >> 6;
    int lr = l & 15, lq = l >> 4;
    int n0 = blockIdx.x * 4;

    // phase 1: stage x*D, zero ys pad cols [130,160)
    #pragma unroll
    for (int it = 0; it < 8; ++it) {
        int f  = tid + it * 512;
        int nn = f >> 10, f4 = f & 1023;
        float4 xa = ((const float4*)(x + (size_t)(n0 + nn) * 4096))[f4];
        float4 da = ((const float4*)D)[f4];
        int rl = nn * 32 + (f4 >> 5);
        int t0 = (f4 & 31) * 4;
        int byte = (rl * 256 + t0 * 2) ^ ((rl & 7) << 4);
        xs8[byte >> 3] = pack4(xa.x * da.x, xa.y * da.y, xa.z * da.z, xa.w * da.w);
    }
    for (int i = tid; i < 3840; i += 512) {
        int rl = i / 30, cp = 130 + i % 30;
        int byte = (rl * 320 + cp * 2) ^ ((rl & 7) << 4);
        *(unsigned short*)(smem + YS_OFF + byte) = 0;
    }
    __syncthreads();

    // stage A: DFT. wave w owns A-rows [w*16, w*16+16)
    int rl_a = w * 16 + lr;
    bf16x8 a[4];
    #pragma unroll
    for (int kb = 0; kb < 4; ++kb) {
        int byte = (rl_a * 256 + kb * 64 + lq * 16) ^ ((rl_a & 7) << 4);
        a[kb] = *(const bf16x8*)(smem + byte);
    }
    __syncthreads();                            // all xs reads done

    {
        f32x4 acc[9];
        #pragma unroll
        for (int c = 0; c < 9; ++c) acc[c] = (f32x4)0.f;
        #pragma unroll
        for (int c = 0; c < 9; ++c)
            #pragma unroll
            for (int kb = 0; kb < 4; ++kb)
                acc[c] = __builtin_amdgcn_mfma_f32_16x16x32_bf16(a[kb], fragB[(c * 4 + kb) * 64 + l], acc[c], 0, 0, 0);

        int rowbase = w * 16 + lq * 4;
        #pragma unroll
        for (int c = 0; c < 9; ++c) {
            int col = c * 16 + lr;
            if (col < 130) {
                int k, reim;
                if (col < 65) { k = col;      reim = 0; }
                else          { k = col - 65; reim = 32; }
                #pragma unroll
                for (int rr = 0; rr < 4; ++rr) {
                    int rl2 = rowbase + rr;
                    int nn = rl2 >> 5, j = rl2 & 31;
                    int byte = (k * 512 + nn * 128 + (reim + j) * 2) ^ ((k & 7) << 4);
                    *(unsigned short*)(smem + byte) = f2bf(acc[c][rr]);
                }
            }
        }
    }
    __syncthreads();

    // stage B: per-k einsum [4n x 64j2] x [64j2 x 64o2] -> ys columns
    for (int k = w; k < 65; k += 8) {
        int xb = k * 512;
        int swz = (k & 7) << 4;
        bf16x8 a2[2];
        a2[0] = *(const bf16x8*)(smem + ((xb + (lr & 3) * 128 +      lq * 16) ^ swz));
        a2[1] = *(const bf16x8*)(smem + ((xb + (lr & 3) * 128 + 64 + lq * 16) ^ swz));
        const unsigned short* bb = BmatT + (size_t)k * 4096 + lr * 64 + lq * 8;
        f32x4 acc2[4];
        #pragma unroll
        for (int cf = 0; cf < 4; ++cf) acc2[cf] = (f32x4)0.f;
        #pragma unroll
        for (int cf = 0; cf < 4; ++cf) {
            bf16x8 b0 = *(const bf16x8*)(bb + cf * 1024);
            bf16x8 b1 = *(const bf16x8*)(bb + cf * 1024 + 32);
            acc2[cf] = __builtin_amdgcn_mfma_f32_16x16x32_bf16(a2[0], b0, acc2[cf], 0, 0, 0);
            acc2[cf] = __builtin_amdgcn_mfma_f32_16x16x32_bf16(a2[1], b1, acc2[cf], 0, 0, 0);
        }
        if (lq == 0) {                          // D rows 0..3 = nn, lanes 0..15
            #pragma unroll
            for (int cf = 0; cf < 4; ++cf) {
                int o2  = cf * 16 + lr;
                int col = (o2 < 32) ? k : 65 + k;
                #pragma unroll
                for (int rr = 0; rr < 4; ++rr) {
                    int row2 = rr * 32 + (o2 & 31);
                    int byte = (row2 * 320 + col * 2) ^ ((row2 & 7) << 4);
                    *(unsigned short*)(smem + YS_OFF + byte) = f2bf(acc2[cf][rr]);
                }
            }
        }
    }
    __syncthreads();

    // stage C: iDFT. wave w owns (nn,o) rows [w*16, w*16+16)
    {
        bf16x8 ac[5];
        #pragma unroll
        for (int kb = 0; kb < 5; ++kb) {
            int byte = (rl_a * 320 + kb * 64 + lq * 16) ^ ((rl_a & 7) << 4);
            ac[kb] = *(const bf16x8*)(smem + YS_OFF + byte);
        }
        f32x4 acc3[8];
        #pragma unroll
        for (int c = 0; c < 8; ++c) acc3[c] = (f32x4)0.f;
        #pragma unroll
        for (int c = 0; c < 8; ++c)
            #pragma unroll
            for (int kb = 0; kb < 5; ++kb)
                acc3[c] = __builtin_amdgcn_mfma_f32_16x16x32_bf16(ac[kb], fragCi[(c * 5 + kb) * 64 + l], acc3[c], 0, 0, 0);

        int rowd = blockIdx.x * 128 + w * 16 + lq * 4;
        #pragma unroll
        for (int c = 0; c < 8; ++c)
            #pragma unroll
            for (int r = 0; r < 4; ++r)
                out[(size_t)(rowd + r) * 128 + c * 16 + lr] = acc3[c][r];
    }
}

// ---------------------------------------------------------------------------
extern "C" void kernel_launch(void* const* d_in, const int* in_sizes, int n_in,
                              void* d_out, int out_size, void* d_ws, size_t ws_size,
                              hipStream_t stream) {
    const float* x = (const float*)d_in[0];
    const float* W = (const float*)d_in[1];
    const float* D = (const float*)d_in[2];
    float* out = (float*)d_out;

    unsigned short* BmatT  = (unsigned short*)d_ws;                 // 266240 bf16
    unsigned short* fragB  = BmatT + 266240;                        // 18432 bf16
    unsigned short* fragCi = fragB + 18432;                         // 20480 bf16
    // total ~610KB

    k_prep <<<96, 256, 0, stream>>>(W, fragB, fragCi, BmatT);
    k_fused<<<256, 512, 0, stream>>>(x, D, (const bf16x8*)fragB, (const bf16x8*)fragCi, BmatT, out);
}